// Round 5
// baseline (1761.391 us; speedup 1.0000x reference)
//
#include <hip/hip_runtime.h>

#define B_ 8
#define R_ 128
#define T_ 64
#define FIN_ 32
#define L_ 64
#define D_ 64
#define H_ 128
#define OUT_ 32
#define ES_ 2048

typedef _Float16 f16;
typedef __attribute__((ext_vector_type(2))) _Float16 f16x2;
typedef __attribute__((ext_vector_type(4))) _Float16 f16x4;
typedef __attribute__((ext_vector_type(8))) _Float16 f16x8;
typedef __attribute__((ext_vector_type(16))) float f32x16;

__device__ __forceinline__ float silu_f(float x) { return x / (1.f + __expf(-x)); }
__device__ __forceinline__ float tanh_f(float x) {
    float e = __expf(2.f * x);
    return 1.f - 2.f / (e + 1.f);
}

// packed x: [128 r][64 c] dwords (hi f16 | lo f16 << 16), 256B row stride
__device__ __forceinline__ uint32_t swzP(uint32_t r, uint32_t cByte) {
    return (r * 256u + cByte) ^ ((r & 15u) << 4);
}
// M^T: [64 c][2 s][128 r] f16, 512B rows
__device__ __forceinline__ uint32_t swzT(uint32_t c, uint32_t s, uint32_t rByte) {
    uint32_t bo = c * 512u + s * 256u + rByte;
    return bo ^ ((c & 31u) << 4);
}

#define XP_OFF 0u        // 32 KB packed x
#define MT_OFF 32768u    // 32 KB M^T hi/lo planes
#define ODE_LDS 65536u   // A staging (64 KB fp32) aliases the whole region

// ---------------------------------------------------------------------------
// prep: deterministic CSR (edges sorted by dst, stable) + permuted per-batch
// edge weights.
// ---------------------------------------------------------------------------
__global__ __launch_bounds__(128) void prep_kernel(
    const int* __restrict__ src, const int* __restrict__ dst,
    const float* __restrict__ space_w,
    int* __restrict__ row_start, int* __restrict__ esrcp, float* __restrict__ wperm) {
    __shared__ int cnt[R_];
    __shared__ int rs[R_ + 1];
    __shared__ int permS[ES_];
    int r = threadIdx.x;
    int c = 0;
    for (int e = 0; e < ES_; ++e) c += (dst[e] == r) ? 1 : 0;
    cnt[r] = c;
    __syncthreads();
    if (r == 0) {
        int a = 0;
        for (int i = 0; i < R_; ++i) { rs[i] = a; a += cnt[i]; }
        rs[R_] = a;
    }
    __syncthreads();
    {
        int k = rs[r];
        for (int e = 0; e < ES_; ++e)
            if (dst[e] == r) permS[k++] = e;
    }
    __syncthreads();
    row_start[r] = rs[r];
    if (r == 0) row_start[R_] = rs[R_];
    for (int e = r; e < ES_; e += 128) esrcp[e] = src[permS[e]];
    for (int i = r; i < B_ * ES_; i += 128) {
        int b = i >> 11;
        int e = i & (ES_ - 1);
        wperm[i] = space_w[b * ES_ + permS[e]];
    }
}

// ---------------------------------------------------------------------------
// encoder: one block per (b,r). W_e1 column in registers (global coalesced),
// xS vectorized at stride 36.
// ---------------------------------------------------------------------------
__global__ __launch_bounds__(256) void encoder_kernel(
    const float* __restrict__ node_feats, const float* __restrict__ eps,
    const float* __restrict__ W_e1, const float* __restrict__ b_e1,
    const float* __restrict__ W_e2, const float* __restrict__ b_e2,
    const float* __restrict__ W_mu, const float* __restrict__ W_sig,
    const float* __restrict__ W_dyn,
    float* __restrict__ Lz, float* __restrict__ Dz, float* __restrict__ dynb) {
    int br = blockIdx.x;
    int tid = threadIdx.x;
    __shared__ __align__(16) float xS[T_ * 36];
    __shared__ __align__(16) float h1[T_ * H_];
    __shared__ float hps[2 * H_];
    __shared__ float hp[H_];
    __shared__ float muS[H_], sgS[H_], vS[H_];

    const float* nf = node_feats + (size_t)br * (T_ * FIN_);
    for (int i = tid; i < T_ * FIN_; i += 256) {
        int t = i >> 5, f = i & 31;
        xS[t * 36 + f] = nf[i];
    }
    if (tid < T_) xS[tid * 36 + 32] = (float)tid * (1.f / 64.f);

    int j = tid & 127;
    int th = tid >> 7;
    float we1r[33];
    #pragma unroll
    for (int k = 0; k < 33; ++k) we1r[k] = W_e1[k * H_ + j];
    __syncthreads();

    float be1 = b_e1[j];
    for (int tt = 0; tt < 32; ++tt) {
        int t = th * 32 + tt;
        float a = be1;
        const float4* xr = (const float4*)(&xS[t * 36]);
        #pragma unroll
        for (int w4 = 0; w4 < 8; ++w4) {
            float4 xv = xr[w4];
            a += xv.x * we1r[w4 * 4 + 0] + xv.y * we1r[w4 * 4 + 1] +
                 xv.z * we1r[w4 * 4 + 2] + xv.w * we1r[w4 * 4 + 3];
        }
        a += xS[t * 36 + 32] * we1r[32];
        h1[t * H_ + j] = silu_f(a);
    }
    __syncthreads();

    float acc[32];
    float be2 = b_e2[j];
    #pragma unroll
    for (int tt = 0; tt < 32; ++tt) acc[tt] = be2;
    for (int kc = 0; kc < 4; ++kc) {
        float wreg[32];
        #pragma unroll
        for (int i2 = 0; i2 < 32; ++i2) wreg[i2] = W_e2[(kc * 32 + i2) * H_ + j];
        #pragma unroll
        for (int tt = 0; tt < 32; ++tt) {
            int t = th * 32 + tt;
            const float4* hrow = (const float4*)(&h1[t * H_ + kc * 32]);
            float s = 0.f;
            #pragma unroll
            for (int w4 = 0; w4 < 8; ++w4) {
                float4 hv = hrow[w4];
                s += hv.x * wreg[w4 * 4 + 0] + hv.y * wreg[w4 * 4 + 1] +
                     hv.z * wreg[w4 * 4 + 2] + hv.w * wreg[w4 * 4 + 3];
            }
            acc[tt] += s;
        }
    }
    float msum = 0.f;
    #pragma unroll
    for (int tt = 0; tt < 32; ++tt) msum += silu_f(acc[tt]);
    hps[th * H_ + j] = msum;
    __syncthreads();
    if (tid < H_) hp[tid] = (hps[tid] + hps[H_ + tid]) * (1.f / 64.f);
    __syncthreads();

    {
        const float* Wm = (th == 0) ? W_mu : W_sig;
        float a = 0.f;
        #pragma unroll 4
        for (int k = 0; k < H_; ++k) a += hp[k] * Wm[k * H_ + j];
        if (th == 0) muS[j] = a; else sgS[j] = a;
    }
    __syncthreads();
    if (tid < H_) {
        float sig = 0.1f + 0.9f / (1.f + __expf(-sgS[tid]));
        float v = muS[tid] + sig * eps[(size_t)br * H_ + tid];
        vS[tid] = v;
        if (tid < L_) Lz[(size_t)br * L_ + tid] = v;
        else          Dz[(size_t)br * D_ + (tid - L_)] = v;
    }
    __syncthreads();
    if (tid < L_) {
        float a = 0.f;
        #pragma unroll 4
        for (int k = 0; k < D_; ++k) a += vS[L_ + k] * W_dyn[k * L_ + tid];
        dynb[(size_t)br * L_ + tid] = a;
    }
}

// ---------------------------------------------------------------------------
// ode (MFMA, associativity-restructured): one block per batch, 8 waves.
//   phase1: S = x@Wself (+dyn, stays in regs), M = x@Wmsg; write M^T (hi/lo)
//   phase2: accK = S + A@M (A-frags static in VGPR); tanh; RK4; write packed x
// Weights Wself/Wmsg live as B-fragments in VGPRs (static). x packed (hi,lo)
// per dword. 3-product f16 hi/lo emulation throughout. 2 barriers/stage.
// ---------------------------------------------------------------------------
__global__ __launch_bounds__(512, 2) void ode_kernel(
    const float* __restrict__ Lz, const float* __restrict__ dynb,
    const float* __restrict__ W_msg, const float* __restrict__ W_self,
    const float* __restrict__ b_ode,
    const int* __restrict__ row_start, const int* __restrict__ esrcp,
    const float* __restrict__ wperm,
    float* __restrict__ traj) {
    const int b = blockIdx.x;
    const int tid = threadIdx.x;
    const int lane = tid & 63;
    const int w = tid >> 6;          // 0..7
    const int rb = w & 3;            // output row block (32 rows)
    const int cb = w >> 2;           // output col block (32 cols)
    const int l31 = lane & 31;
    const int h = lane >> 5;
    const int cc = cb * 32 + l31;    // this thread's output column (0..63)

    extern __shared__ char sm[];
    float* Af = (float*)sm;          // fp32 A staging [128][128], aliases XP/MT

    // ---- static weight B-fragments -> VGPRs (hi/lo) ----
    f16x8 wsH[4], wsL[4], wmH[4], wmL[4];
    #pragma unroll
    for (int m = 0; m < 4; ++m) {
        f16x8 sh, sl, mh, ml;
        #pragma unroll
        for (int i = 0; i < 8; ++i) {
            int k = m * 16 + 8 * h + i;
            float vs = W_self[k * 64 + cc];
            f16 s0 = (f16)vs;
            sh[i] = s0; sl[i] = (f16)(vs - (float)s0);
            float vm = W_msg[k * 64 + cc];
            f16 m0 = (f16)vm;
            mh[i] = m0; ml[i] = (f16)(vm - (float)m0);
        }
        wsH[m] = sh; wsL[m] = sl; wmH[m] = mh; wmL[m] = ml;
    }

    // ---- zero A, deterministic CSR build ----
    for (int i = tid; i < 128 * 128; i += 512) Af[i] = 0.f;
    __syncthreads();
    if (tid < 128) {
        int e0 = row_start[tid], e1 = row_start[tid + 1];
        for (int e = e0; e < e1; ++e)
            Af[tid * 128 + esrcp[e]] += wperm[b * ES_ + e];
    }
    __syncthreads();

    // ---- A fragments -> VGPRs (hi/lo) ----
    f16x8 aH[8], aL[8];
    {
        int row = rb * 32 + l31;
        #pragma unroll
        for (int m = 0; m < 8; ++m) {
            const float* p = Af + row * 128 + m * 16 + h * 8;
            f16x8 vh, vl;
            #pragma unroll
            for (int i = 0; i < 8; ++i) {
                float v = p[i];
                f16 hi = (f16)v;
                vh[i] = hi;
                vl[i] = (f16)(v - (float)hi);
            }
            aH[m] = vh;
            aL[m] = vl;
        }
    }

    // ---- per-thread state in C-layout ----
    float xb[16], ks[16], dnb[16];
    {
        float bo = b_ode[cc];
        #pragma unroll
        for (int i = 0; i < 16; ++i) {
            int r = rb * 32 + (i & 3) + 8 * (i >> 2) + 4 * h;
            size_t o = ((size_t)(b * R_ + r)) * L_ + cc;
            xb[i] = Lz[o];
            dnb[i] = dynb[o] + bo;
        }
    }
    __syncthreads();  // Af dead from here; LDS reused as XP/MT

    // ---- write initial packed x ----
    #pragma unroll
    for (int i = 0; i < 16; ++i) {
        int r = rb * 32 + (i & 3) + 8 * (i >> 2) + 4 * h;
        f16 hi = (f16)xb[i];
        f16x2 pk; pk[0] = hi; pk[1] = (f16)(xb[i] - (float)hi);
        *(f16x2*)(sm + XP_OFF + swzP(r, cc * 4)) = pk;
    }
    __syncthreads();

    const int rowx = rb * 32 + l31;   // A-operand row for this lane

    for (int n = 0; n < T_; ++n) {
        #pragma unroll
        for (int i = 0; i < 16; ++i) ks[i] = 0.f;
        for (int s4 = 0; s4 < 4; ++s4) {
            const float wk = (s4 == 1 || s4 == 2) ? 2.f : 1.f;
            const float cn = (s4 < 2) ? 0.05f : 0.1f;

            // ===== phase 1: S = x@Wself (+dyn), M = x@Wmsg =====
            f32x16 accS, accM = {};
            #pragma unroll
            for (int i = 0; i < 16; ++i) accS[i] = dnb[i];
            #pragma unroll
            for (int m = 0; m < 4; ++m) {
                uint32_t cByte = (m * 16 + 8 * h) * 4;
                uint4 p0 = *(const uint4*)(sm + XP_OFF + swzP(rowx, cByte));
                uint4 p1 = *(const uint4*)(sm + XP_OFF + swzP(rowx, cByte + 16));
                union { uint32_t u[4]; f16x8 v; } axh, axl;
                axh.u[0] = (p0.x & 0xFFFFu) | (p0.y << 16);
                axh.u[1] = (p0.z & 0xFFFFu) | (p0.w << 16);
                axh.u[2] = (p1.x & 0xFFFFu) | (p1.y << 16);
                axh.u[3] = (p1.z & 0xFFFFu) | (p1.w << 16);
                axl.u[0] = (p0.x >> 16) | (p0.y & 0xFFFF0000u);
                axl.u[1] = (p0.z >> 16) | (p0.w & 0xFFFF0000u);
                axl.u[2] = (p1.x >> 16) | (p1.y & 0xFFFF0000u);
                axl.u[3] = (p1.z >> 16) | (p1.w & 0xFFFF0000u);
                accS = __builtin_amdgcn_mfma_f32_32x32x16_f16(axh.v, wsH[m], accS, 0, 0, 0);
                accM = __builtin_amdgcn_mfma_f32_32x32x16_f16(axh.v, wmH[m], accM, 0, 0, 0);
                accS = __builtin_amdgcn_mfma_f32_32x32x16_f16(axl.v, wsH[m], accS, 0, 0, 0);
                accM = __builtin_amdgcn_mfma_f32_32x32x16_f16(axl.v, wmH[m], accM, 0, 0, 0);
                accS = __builtin_amdgcn_mfma_f32_32x32x16_f16(axh.v, wsL[m], accS, 0, 0, 0);
                accM = __builtin_amdgcn_mfma_f32_32x32x16_f16(axh.v, wmL[m], accM, 0, 0, 0);
            }
            // write M^T hi/lo (rows 4q consecutive per b64)
            #pragma unroll
            for (int q = 0; q < 4; ++q) {
                int rbase = rb * 32 + 8 * q + 4 * h;
                f16x4 vh, vl;
                #pragma unroll
                for (int u = 0; u < 4; ++u) {
                    float t = accM[4 * q + u];
                    f16 hi = (f16)t;
                    vh[u] = hi;
                    vl[u] = (f16)(t - (float)hi);
                }
                *(f16x4*)(sm + MT_OFF + swzT(cc, 0, rbase * 2)) = vh;
                *(f16x4*)(sm + MT_OFF + swzT(cc, 1, rbase * 2)) = vl;
            }
            __syncthreads();

            // ===== phase 2: accK = S + A@M (two independent chains) =====
            f32x16 accP = {}, accQ = {};
            #pragma unroll
            for (int m = 0; m < 8; ++m) {
                f16x8 mtH = *(const f16x8*)(sm + MT_OFF + swzT(cc, 0, (m * 16 + 8 * h) * 2));
                f16x8 mtL = *(const f16x8*)(sm + MT_OFF + swzT(cc, 1, (m * 16 + 8 * h) * 2));
                if (m & 1) {
                    accQ = __builtin_amdgcn_mfma_f32_32x32x16_f16(aH[m], mtH, accQ, 0, 0, 0);
                    accQ = __builtin_amdgcn_mfma_f32_32x32x16_f16(aL[m], mtH, accQ, 0, 0, 0);
                    accQ = __builtin_amdgcn_mfma_f32_32x32x16_f16(aH[m], mtL, accQ, 0, 0, 0);
                } else {
                    accP = __builtin_amdgcn_mfma_f32_32x32x16_f16(aH[m], mtH, accP, 0, 0, 0);
                    accP = __builtin_amdgcn_mfma_f32_32x32x16_f16(aL[m], mtH, accP, 0, 0, 0);
                    accP = __builtin_amdgcn_mfma_f32_32x32x16_f16(aH[m], mtL, accP, 0, 0, 0);
                }
            }
            // epilogue: tanh, RK4, write packed new x
            float xn_[16];
            #pragma unroll
            for (int i = 0; i < 16; ++i) {
                float kv = tanh_f(accS[i] + accP[i] + accQ[i]);
                ks[i] += wk * kv;
                xn_[i] = (s4 < 3) ? (xb[i] + cn * kv) : (xb[i] + (0.1f / 6.f) * ks[i]);
            }
            if (s4 == 3) {
                #pragma unroll
                for (int i = 0; i < 16; ++i) xb[i] = xn_[i];
            }
            #pragma unroll
            for (int i = 0; i < 16; ++i) {
                int r = rb * 32 + (i & 3) + 8 * (i >> 2) + 4 * h;
                f16 hi = (f16)xn_[i];
                f16x2 pk; pk[0] = hi; pk[1] = (f16)(xn_[i] - (float)hi);
                *(f16x2*)(sm + XP_OFF + swzP(r, cc * 4)) = pk;
            }
            if (s4 == 3) {
                #pragma unroll
                for (int i = 0; i < 16; ++i) {
                    int r = rb * 32 + (i & 3) + 8 * (i >> 2) + 4 * h;
                    traj[(((size_t)b * T_ + n) * R_ + r) * L_ + cc] = xb[i];
                }
            }
            __syncthreads();
        }
    }
}

// ---------------------------------------------------------------------------
// decoder: one block per (b,r), one-hot rid exploited as row lookup.
// ---------------------------------------------------------------------------
__global__ __launch_bounds__(256) void decoder_kernel(
    const float* __restrict__ traj, const float* __restrict__ Dz,
    const float* __restrict__ W_d1, const float* __restrict__ b_d1,
    const float* __restrict__ W_d2, const float* __restrict__ b_d2,
    float* __restrict__ y) {
    int br = blockIdx.x;
    int b = br >> 7;
    int r = br & 127;
    int tid = threadIdx.x;
    __shared__ __align__(16) float trajS[32 * L_];
    __shared__ __align__(16) float hS[32 * H_];
    __shared__ float dzS[D_];
    __shared__ float baseS[H_];

    int j = tid & 127;
    int th = tid >> 7;
    if (tid < D_) dzS[tid] = Dz[(size_t)br * D_ + tid];
    __syncthreads();

    float wcol[64];
    #pragma unroll
    for (int k = 0; k < 64; ++k) wcol[k] = W_d1[k * H_ + j];
    float wt = W_d1[128 * H_ + j];
    if (th == 0) {
        float a = b_d1[j] + W_d1[(129 + r) * H_ + j];
        #pragma unroll 4
        for (int k = 0; k < D_; ++k) a += dzS[k] * W_d1[(64 + k) * H_ + j];
        baseS[j] = a;
    }
    __syncthreads();
    float bb = baseS[j];

    for (int half = 0; half < 2; ++half) {
        for (int i = tid; i < 32 * L_; i += 256) {
            int tt = i >> 6, l = i & 63;
            trajS[i] = traj[(((size_t)b * T_ + half * 32 + tt) * R_ + r) * L_ + l];
        }
        __syncthreads();
        #pragma unroll
        for (int tt = 0; tt < 16; ++tt) {
            int tl = th * 16 + tt;
            int t = half * 32 + tl;
            float a = bb + (float)t * (1.f / 64.f) * wt;
            const float4* tr4 = (const float4*)(&trajS[tl * L_]);
            #pragma unroll
            for (int kb = 0; kb < 16; ++kb) {
                float4 tv = tr4[kb];
                a += tv.x * wcol[kb * 4 + 0] + tv.y * wcol[kb * 4 + 1] +
                     tv.z * wcol[kb * 4 + 2] + tv.w * wcol[kb * 4 + 3];
            }
            hS[tl * H_ + j] = silu_f(a);
        }
        __syncthreads();
        {
            int o = tid & 31, q = tid >> 5;
            float acc2[4];
            float bd2 = b_d2[o];
            #pragma unroll
            for (int u = 0; u < 4; ++u) acc2[u] = bd2;
            for (int jc = 0; jc < 4; ++jc) {
                float wreg[32];
                #pragma unroll
                for (int i2 = 0; i2 < 32; ++i2) wreg[i2] = W_d2[(jc * 32 + i2) * OUT_ + o];
                #pragma unroll
                for (int u = 0; u < 4; ++u) {
                    int tl = q * 4 + u;
                    const float4* h4 = (const float4*)(&hS[tl * H_ + jc * 32]);
                    float s2 = 0.f;
                    #pragma unroll
                    for (int w4 = 0; w4 < 8; ++w4) {
                        float4 hv = h4[w4];
                        s2 += hv.x * wreg[w4 * 4 + 0] + hv.y * wreg[w4 * 4 + 1] +
                              hv.z * wreg[w4 * 4 + 2] + hv.w * wreg[w4 * 4 + 3];
                    }
                    acc2[u] += s2;
                }
            }
            #pragma unroll
            for (int u = 0; u < 4; ++u) {
                int t = half * 32 + q * 4 + u;
                y[((size_t)br * T_ + t) * OUT_ + o] = acc2[u];
            }
        }
        __syncthreads();
    }
}

extern "C" void kernel_launch(void* const* d_in, const int* in_sizes, int n_in,
                              void* d_out, int out_size, void* d_ws, size_t ws_size,
                              hipStream_t stream) {
    const float* node_feats = (const float*)d_in[0];
    const float* eps_       = (const float*)d_in[1];
    const float* space_w    = (const float*)d_in[2];
    const int*   src        = (const int*)d_in[3];
    const int*   dst        = (const int*)d_in[4];
    const float* W_e1 = (const float*)d_in[5];
    const float* b_e1 = (const float*)d_in[6];
    const float* W_e2 = (const float*)d_in[7];
    const float* b_e2 = (const float*)d_in[8];
    const float* W_mu = (const float*)d_in[9];
    const float* W_sig = (const float*)d_in[10];
    const float* W_msg = (const float*)d_in[11];
    const float* W_self = (const float*)d_in[12];
    const float* W_dyn = (const float*)d_in[13];
    const float* b_ode = (const float*)d_in[14];
    const float* W_d1 = (const float*)d_in[15];
    const float* b_d1 = (const float*)d_in[16];
    const float* W_d2 = (const float*)d_in[17];
    const float* b_d2 = (const float*)d_in[18];
    float* out = (float*)d_out;

    float* f_ws = (float*)d_ws;
    float* Lz    = f_ws;                              // 65536
    float* Dz    = Lz + B_ * R_ * L_;                 // 65536
    float* dynb  = Dz + B_ * R_ * D_;                 // 65536
    float* traj  = dynb + B_ * R_ * L_;               // 4194304
    float* wperm = traj + (size_t)B_ * T_ * R_ * L_;  // 16384
    int* row_start = (int*)(wperm + B_ * ES_);        // 132
    int* esrcp     = row_start + 132;                 // 2048

    prep_kernel<<<1, 128, 0, stream>>>(src, dst, space_w, row_start, esrcp, wperm);
    encoder_kernel<<<B_ * R_, 256, 0, stream>>>(node_feats, eps_, W_e1, b_e1, W_e2, b_e2,
                                                W_mu, W_sig, W_dyn, Lz, Dz, dynb);
    ode_kernel<<<B_, 512, ODE_LDS, stream>>>(Lz, dynb, W_msg, W_self, b_ode,
                                             row_start, esrcp, wperm, traj);
    decoder_kernel<<<B_ * R_, 256, 0, stream>>>(traj, Dz, W_d1, b_d1, W_d2, b_d2, out);
}

// Round 6
// 1638.503 us; speedup vs baseline: 1.0750x; 1.0750x over previous
//
#include <hip/hip_runtime.h>

#define B_ 8
#define R_ 128
#define T_ 64
#define FIN_ 32
#define L_ 64
#define D_ 64
#define H_ 128
#define OUT_ 32
#define ES_ 2048

typedef _Float16 f16;
typedef __attribute__((ext_vector_type(2))) _Float16 f16x2;
typedef __attribute__((ext_vector_type(4))) _Float16 f16x4;
typedef __attribute__((ext_vector_type(8))) _Float16 f16x8;
typedef __attribute__((ext_vector_type(16))) float f32x16;

__device__ __forceinline__ float silu_f(float x) { return x / (1.f + __expf(-x)); }
__device__ __forceinline__ float tanh_f(float x) {
    float e = __expf(2.f * x);
    return 1.f - 2.f / (e + 1.f);
}

// 256B-stride hi/lo-interleaved arrays ([dim][2][64] f16): XOR row into the
// 16B-granule bits -> 16 granules, 2-way max aliasing (free).
__device__ __forceinline__ uint32_t swz256(uint32_t row, uint32_t s, uint32_t colByte) {
    uint32_t bo = row * 256u + s * 128u + colByte;
    return bo ^ ((row & 15u) << 4);
}
// M^T: [64 c][2 s][128 r] f16, 512B rows: 32 granules, conflict-free.
__device__ __forceinline__ uint32_t swzT(uint32_t c, uint32_t s, uint32_t rByte) {
    uint32_t bo = c * 512u + s * 256u + rByte;
    return bo ^ ((c & 31u) << 4);
}

#define XROW_OFF 0u      // 32 KB x hi/lo  [128 r][2 s][64 c] f16
#define MT_OFF   32768u  // 32 KB M^T      [64 c][2 s][128 r] f16
#define WS_OFF   65536u  // 16 KB Wself^T  [64 j][2 s][64 k] f16
#define WM_OFF   81920u  // 16 KB Wmsg^T   [64 j][2 s][64 k] f16
#define ODE_LDS  98304u  // A staging (64 KB fp32) aliases XROW+MT pre-loop

// ---------------------------------------------------------------------------
// prep: deterministic CSR (edges sorted by dst, stable) + permuted per-batch
// edge weights.
// ---------------------------------------------------------------------------
__global__ __launch_bounds__(128) void prep_kernel(
    const int* __restrict__ src, const int* __restrict__ dst,
    const float* __restrict__ space_w,
    int* __restrict__ row_start, int* __restrict__ esrcp, float* __restrict__ wperm) {
    __shared__ int cnt[R_];
    __shared__ int rs[R_ + 1];
    __shared__ int permS[ES_];
    int r = threadIdx.x;
    int c = 0;
    for (int e = 0; e < ES_; ++e) c += (dst[e] == r) ? 1 : 0;
    cnt[r] = c;
    __syncthreads();
    if (r == 0) {
        int a = 0;
        for (int i = 0; i < R_; ++i) { rs[i] = a; a += cnt[i]; }
        rs[R_] = a;
    }
    __syncthreads();
    {
        int k = rs[r];
        for (int e = 0; e < ES_; ++e)
            if (dst[e] == r) permS[k++] = e;
    }
    __syncthreads();
    row_start[r] = rs[r];
    if (r == 0) row_start[R_] = rs[R_];
    for (int e = r; e < ES_; e += 128) esrcp[e] = src[permS[e]];
    for (int i = r; i < B_ * ES_; i += 128) {
        int b = i >> 11;
        int e = i & (ES_ - 1);
        wperm[i] = space_w[b * ES_ + permS[e]];
    }
}

// ---------------------------------------------------------------------------
// encoder: one block per (b,r).
// ---------------------------------------------------------------------------
__global__ __launch_bounds__(256) void encoder_kernel(
    const float* __restrict__ node_feats, const float* __restrict__ eps,
    const float* __restrict__ W_e1, const float* __restrict__ b_e1,
    const float* __restrict__ W_e2, const float* __restrict__ b_e2,
    const float* __restrict__ W_mu, const float* __restrict__ W_sig,
    const float* __restrict__ W_dyn,
    float* __restrict__ Lz, float* __restrict__ Dz, float* __restrict__ dynb) {
    int br = blockIdx.x;
    int tid = threadIdx.x;
    __shared__ __align__(16) float xS[T_ * 36];
    __shared__ __align__(16) float h1[T_ * H_];
    __shared__ float hps[2 * H_];
    __shared__ float hp[H_];
    __shared__ float muS[H_], sgS[H_], vS[H_];

    const float* nf = node_feats + (size_t)br * (T_ * FIN_);
    for (int i = tid; i < T_ * FIN_; i += 256) {
        int t = i >> 5, f = i & 31;
        xS[t * 36 + f] = nf[i];
    }
    if (tid < T_) xS[tid * 36 + 32] = (float)tid * (1.f / 64.f);

    int j = tid & 127;
    int th = tid >> 7;
    float we1r[33];
    #pragma unroll
    for (int k = 0; k < 33; ++k) we1r[k] = W_e1[k * H_ + j];
    __syncthreads();

    float be1 = b_e1[j];
    for (int tt = 0; tt < 32; ++tt) {
        int t = th * 32 + tt;
        float a = be1;
        const float4* xr = (const float4*)(&xS[t * 36]);
        #pragma unroll
        for (int w4 = 0; w4 < 8; ++w4) {
            float4 xv = xr[w4];
            a += xv.x * we1r[w4 * 4 + 0] + xv.y * we1r[w4 * 4 + 1] +
                 xv.z * we1r[w4 * 4 + 2] + xv.w * we1r[w4 * 4 + 3];
        }
        a += xS[t * 36 + 32] * we1r[32];
        h1[t * H_ + j] = silu_f(a);
    }
    __syncthreads();

    float acc[32];
    float be2 = b_e2[j];
    #pragma unroll
    for (int tt = 0; tt < 32; ++tt) acc[tt] = be2;
    for (int kc = 0; kc < 4; ++kc) {
        float wreg[32];
        #pragma unroll
        for (int i2 = 0; i2 < 32; ++i2) wreg[i2] = W_e2[(kc * 32 + i2) * H_ + j];
        #pragma unroll
        for (int tt = 0; tt < 32; ++tt) {
            int t = th * 32 + tt;
            const float4* hrow = (const float4*)(&h1[t * H_ + kc * 32]);
            float s = 0.f;
            #pragma unroll
            for (int w4 = 0; w4 < 8; ++w4) {
                float4 hv = hrow[w4];
                s += hv.x * wreg[w4 * 4 + 0] + hv.y * wreg[w4 * 4 + 1] +
                     hv.z * wreg[w4 * 4 + 2] + hv.w * wreg[w4 * 4 + 3];
            }
            acc[tt] += s;
        }
    }
    float msum = 0.f;
    #pragma unroll
    for (int tt = 0; tt < 32; ++tt) msum += silu_f(acc[tt]);
    hps[th * H_ + j] = msum;
    __syncthreads();
    if (tid < H_) hp[tid] = (hps[tid] + hps[H_ + tid]) * (1.f / 64.f);
    __syncthreads();

    {
        const float* Wm = (th == 0) ? W_mu : W_sig;
        float a = 0.f;
        #pragma unroll 4
        for (int k = 0; k < H_; ++k) a += hp[k] * Wm[k * H_ + j];
        if (th == 0) muS[j] = a; else sgS[j] = a;
    }
    __syncthreads();
    if (tid < H_) {
        float sig = 0.1f + 0.9f / (1.f + __expf(-sgS[tid]));
        float v = muS[tid] + sig * eps[(size_t)br * H_ + tid];
        vS[tid] = v;
        if (tid < L_) Lz[(size_t)br * L_ + tid] = v;
        else          Dz[(size_t)br * D_ + (tid - L_)] = v;
    }
    __syncthreads();
    if (tid < L_) {
        float a = 0.f;
        #pragma unroll 4
        for (int k = 0; k < D_; ++k) a += vS[L_ + k] * W_dyn[k * L_ + tid];
        dynb[(size_t)br * L_ + tid] = a;
    }
}

// ---------------------------------------------------------------------------
// ode (MFMA): one block per batch, 8 waves.
//   phase1: S = dyn + x@Wself (stays in AGPRs), M = x@Wmsg; write M^T hi/lo
//   phase2: k = tanh(S + A@M) via 3 indep chains; RK4; write x hi/lo planes
// Weights + x in LDS (hi/lo-interleaved rows, swz256) -> ~100 free VGPRs so
// the scheduler can pipeline ds_reads across the m-loops (R4 lesson: register
// slack beats DS-count). A fragments static in VGPRs. 2 barriers/stage.
// ---------------------------------------------------------------------------
__global__ __launch_bounds__(512, 2) void ode_kernel(
    const float* __restrict__ Lz, const float* __restrict__ dynb,
    const float* __restrict__ W_msg, const float* __restrict__ W_self,
    const float* __restrict__ b_ode,
    const int* __restrict__ row_start, const int* __restrict__ esrcp,
    const float* __restrict__ wperm,
    float* __restrict__ traj) {
    const int b = blockIdx.x;
    const int tid = threadIdx.x;
    const int lane = tid & 63;
    const int w = tid >> 6;          // 0..7
    const int rb = w & 3;            // output row block (32 rows)
    const int cb = w >> 2;           // output col block (32 cols)
    const int l31 = lane & 31;
    const int h = lane >> 5;
    const int cc = cb * 32 + l31;    // this thread's output column (0..63)

    extern __shared__ char sm[];
    float* Af = (float*)sm;          // fp32 A staging [128][128], aliases XROW+MT

    // ---- static weights -> LDS (hi/lo, transposed: WT[j][s][k] = W[k][j]) ----
    for (int idx = tid; idx < 4096; idx += 512) {
        int j = idx & 63, k = idx >> 6;
        float vs = W_self[k * 64 + j];
        f16 sh = (f16)vs;
        *(f16*)(sm + WS_OFF + swz256(j, 0, k * 2)) = sh;
        *(f16*)(sm + WS_OFF + swz256(j, 1, k * 2)) = (f16)(vs - (float)sh);
        float vm = W_msg[k * 64 + j];
        f16 mh = (f16)vm;
        *(f16*)(sm + WM_OFF + swz256(j, 0, k * 2)) = mh;
        *(f16*)(sm + WM_OFF + swz256(j, 1, k * 2)) = (f16)(vm - (float)mh);
    }
    // ---- zero A, deterministic CSR build ----
    for (int i = tid; i < 128 * 128; i += 512) Af[i] = 0.f;
    __syncthreads();
    if (tid < 128) {
        int e0 = row_start[tid], e1 = row_start[tid + 1];
        for (int e = e0; e < e1; ++e)
            Af[tid * 128 + esrcp[e]] += wperm[b * ES_ + e];
    }
    __syncthreads();

    // ---- A fragments -> VGPRs (hi/lo) ----
    f16x8 aH[8], aL[8];
    {
        int row = rb * 32 + l31;
        #pragma unroll
        for (int m = 0; m < 8; ++m) {
            const float* p = Af + row * 128 + m * 16 + h * 8;
            f16x8 vh, vl;
            #pragma unroll
            for (int i = 0; i < 8; ++i) {
                float v = p[i];
                f16 hi = (f16)v;
                vh[i] = hi;
                vl[i] = (f16)(v - (float)hi);
            }
            aH[m] = vh;
            aL[m] = vl;
        }
    }

    // ---- per-thread state in C-layout ----
    float xb[16], ks[16], dnb[16];
    {
        float bo = b_ode[cc];
        #pragma unroll
        for (int i = 0; i < 16; ++i) {
            int r = rb * 32 + (i & 3) + 8 * (i >> 2) + 4 * h;
            size_t o = ((size_t)(b * R_ + r)) * L_ + cc;
            xb[i] = Lz[o];
            dnb[i] = dynb[o] + bo;
        }
    }
    __syncthreads();  // Af dead; LDS region 0..64KB becomes XROW+MT

    // ---- write initial x (hi/lo planes) ----
    #pragma unroll
    for (int i = 0; i < 16; ++i) {
        int r = rb * 32 + (i & 3) + 8 * (i >> 2) + 4 * h;
        f16 hi = (f16)xb[i];
        *(f16*)(sm + XROW_OFF + swz256(r, 0, cc * 2)) = hi;
        *(f16*)(sm + XROW_OFF + swz256(r, 1, cc * 2)) = (f16)(xb[i] - (float)hi);
    }
    __syncthreads();

    const int rowx = rb * 32 + l31;   // A-operand row for this lane

    for (int n = 0; n < T_; ++n) {
        #pragma unroll
        for (int i = 0; i < 16; ++i) ks[i] = 0.f;
        for (int s4 = 0; s4 < 4; ++s4) {
            const float wk = (s4 == 1 || s4 == 2) ? 2.f : 1.f;
            const float cn = (s4 < 2) ? 0.05f : 0.1f;

            // ===== phase 1: S = dyn + x@Wself, M = x@Wmsg =====
            // prefetch all x fragments first (8 b128), then the W m-loop
            f16x8 xh[4], xl[4];
            #pragma unroll
            for (int m = 0; m < 4; ++m) {
                uint32_t kB = (m * 16 + 8 * h) * 2;
                xh[m] = *(const f16x8*)(sm + XROW_OFF + swz256(rowx, 0, kB));
                xl[m] = *(const f16x8*)(sm + XROW_OFF + swz256(rowx, 1, kB));
            }
            f32x16 aS, aM = {};
            #pragma unroll
            for (int i = 0; i < 16; ++i) aS[i] = dnb[i];
            #pragma unroll
            for (int m = 0; m < 4; ++m) {
                uint32_t kB = (m * 16 + 8 * h) * 2;
                f16x8 wsH = *(const f16x8*)(sm + WS_OFF + swz256(cc, 0, kB));
                f16x8 wsL = *(const f16x8*)(sm + WS_OFF + swz256(cc, 1, kB));
                f16x8 wmH = *(const f16x8*)(sm + WM_OFF + swz256(cc, 0, kB));
                f16x8 wmL = *(const f16x8*)(sm + WM_OFF + swz256(cc, 1, kB));
                aS = __builtin_amdgcn_mfma_f32_32x32x16_f16(xh[m], wsH, aS, 0, 0, 0);
                aM = __builtin_amdgcn_mfma_f32_32x32x16_f16(xh[m], wmH, aM, 0, 0, 0);
                aS = __builtin_amdgcn_mfma_f32_32x32x16_f16(xl[m], wsH, aS, 0, 0, 0);
                aM = __builtin_amdgcn_mfma_f32_32x32x16_f16(xl[m], wmH, aM, 0, 0, 0);
                aS = __builtin_amdgcn_mfma_f32_32x32x16_f16(xh[m], wsL, aS, 0, 0, 0);
                aM = __builtin_amdgcn_mfma_f32_32x32x16_f16(xh[m], wmL, aM, 0, 0, 0);
            }
            // write M^T hi/lo (rows 4q consecutive per b64)
            #pragma unroll
            for (int q = 0; q < 4; ++q) {
                int rbase = rb * 32 + 8 * q + 4 * h;
                f16x4 vh, vl;
                #pragma unroll
                for (int u = 0; u < 4; ++u) {
                    float t = aM[4 * q + u];
                    f16 hi = (f16)t;
                    vh[u] = hi;
                    vl[u] = (f16)(t - (float)hi);
                }
                *(f16x4*)(sm + MT_OFF + swzT(cc, 0, rbase * 2)) = vh;
                *(f16x4*)(sm + MT_OFF + swzT(cc, 1, rbase * 2)) = vl;
            }
            __syncthreads();

            // ===== phase 2: accK = S + A@M (3 independent chains) =====
            f32x16 e0 = {}, e1 = {}, e2 = {};
            #pragma unroll
            for (int m = 0; m < 8; ++m) {
                f16x8 mtH = *(const f16x8*)(sm + MT_OFF + swzT(cc, 0, (m * 16 + 8 * h) * 2));
                f16x8 mtL = *(const f16x8*)(sm + MT_OFF + swzT(cc, 1, (m * 16 + 8 * h) * 2));
                if (m < 3) {
                    e0 = __builtin_amdgcn_mfma_f32_32x32x16_f16(aH[m], mtH, e0, 0, 0, 0);
                    e0 = __builtin_amdgcn_mfma_f32_32x32x16_f16(aL[m], mtH, e0, 0, 0, 0);
                    e0 = __builtin_amdgcn_mfma_f32_32x32x16_f16(aH[m], mtL, e0, 0, 0, 0);
                } else if (m < 6) {
                    e1 = __builtin_amdgcn_mfma_f32_32x32x16_f16(aH[m], mtH, e1, 0, 0, 0);
                    e1 = __builtin_amdgcn_mfma_f32_32x32x16_f16(aL[m], mtH, e1, 0, 0, 0);
                    e1 = __builtin_amdgcn_mfma_f32_32x32x16_f16(aH[m], mtL, e1, 0, 0, 0);
                } else {
                    e2 = __builtin_amdgcn_mfma_f32_32x32x16_f16(aH[m], mtH, e2, 0, 0, 0);
                    e2 = __builtin_amdgcn_mfma_f32_32x32x16_f16(aL[m], mtH, e2, 0, 0, 0);
                    e2 = __builtin_amdgcn_mfma_f32_32x32x16_f16(aH[m], mtL, e2, 0, 0, 0);
                }
            }
            // epilogue: tanh, RK4, write x hi/lo planes
            float xn_[16];
            #pragma unroll
            for (int i = 0; i < 16; ++i) {
                float kv = tanh_f(aS[i] + e0[i] + e1[i] + e2[i]);
                ks[i] += wk * kv;
                xn_[i] = (s4 < 3) ? (xb[i] + cn * kv) : (xb[i] + (0.1f / 6.f) * ks[i]);
            }
            if (s4 == 3) {
                #pragma unroll
                for (int i = 0; i < 16; ++i) xb[i] = xn_[i];
            }
            #pragma unroll
            for (int i = 0; i < 16; ++i) {
                int r = rb * 32 + (i & 3) + 8 * (i >> 2) + 4 * h;
                f16 hi = (f16)xn_[i];
                *(f16*)(sm + XROW_OFF + swz256(r, 0, cc * 2)) = hi;
                *(f16*)(sm + XROW_OFF + swz256(r, 1, cc * 2)) = (f16)(xn_[i] - (float)hi);
            }
            if (s4 == 3) {
                #pragma unroll
                for (int i = 0; i < 16; ++i) {
                    int r = rb * 32 + (i & 3) + 8 * (i >> 2) + 4 * h;
                    traj[(((size_t)b * T_ + n) * R_ + r) * L_ + cc] = xb[i];
                }
            }
            __syncthreads();
        }
    }
}

// ---------------------------------------------------------------------------
// decoder: one block per (b,r), one-hot rid exploited as row lookup.
// ---------------------------------------------------------------------------
__global__ __launch_bounds__(256) void decoder_kernel(
    const float* __restrict__ traj, const float* __restrict__ Dz,
    const float* __restrict__ W_d1, const float* __restrict__ b_d1,
    const float* __restrict__ W_d2, const float* __restrict__ b_d2,
    float* __restrict__ y) {
    int br = blockIdx.x;
    int b = br >> 7;
    int r = br & 127;
    int tid = threadIdx.x;
    __shared__ __align__(16) float trajS[32 * L_];
    __shared__ __align__(16) float hS[32 * H_];
    __shared__ float dzS[D_];
    __shared__ float baseS[H_];

    int j = tid & 127;
    int th = tid >> 7;
    if (tid < D_) dzS[tid] = Dz[(size_t)br * D_ + tid];
    __syncthreads();

    float wcol[64];
    #pragma unroll
    for (int k = 0; k < 64; ++k) wcol[k] = W_d1[k * H_ + j];
    float wt = W_d1[128 * H_ + j];
    if (th == 0) {
        float a = b_d1[j] + W_d1[(129 + r) * H_ + j];
        #pragma unroll 4
        for (int k = 0; k < D_; ++k) a += dzS[k] * W_d1[(64 + k) * H_ + j];
        baseS[j] = a;
    }
    __syncthreads();
    float bb = baseS[j];

    for (int half = 0; half < 2; ++half) {
        for (int i = tid; i < 32 * L_; i += 256) {
            int tt = i >> 6, l = i & 63;
            trajS[i] = traj[(((size_t)b * T_ + half * 32 + tt) * R_ + r) * L_ + l];
        }
        __syncthreads();
        #pragma unroll
        for (int tt = 0; tt < 16; ++tt) {
            int tl = th * 16 + tt;
            int t = half * 32 + tl;
            float a = bb + (float)t * (1.f / 64.f) * wt;
            const float4* tr4 = (const float4*)(&trajS[tl * L_]);
            #pragma unroll
            for (int kb = 0; kb < 16; ++kb) {
                float4 tv = tr4[kb];
                a += tv.x * wcol[kb * 4 + 0] + tv.y * wcol[kb * 4 + 1] +
                     tv.z * wcol[kb * 4 + 2] + tv.w * wcol[kb * 4 + 3];
            }
            hS[tl * H_ + j] = silu_f(a);
        }
        __syncthreads();
        {
            int o = tid & 31, q = tid >> 5;
            float acc2[4];
            float bd2 = b_d2[o];
            #pragma unroll
            for (int u = 0; u < 4; ++u) acc2[u] = bd2;
            for (int jc = 0; jc < 4; ++jc) {
                float wreg[32];
                #pragma unroll
                for (int i2 = 0; i2 < 32; ++i2) wreg[i2] = W_d2[(jc * 32 + i2) * OUT_ + o];
                #pragma unroll
                for (int u = 0; u < 4; ++u) {
                    int tl = q * 4 + u;
                    const float4* h4 = (const float4*)(&hS[tl * H_ + jc * 32]);
                    float s2 = 0.f;
                    #pragma unroll
                    for (int w4 = 0; w4 < 8; ++w4) {
                        float4 hv = h4[w4];
                        s2 += hv.x * wreg[w4 * 4 + 0] + hv.y * wreg[w4 * 4 + 1] +
                              hv.z * wreg[w4 * 4 + 2] + hv.w * wreg[w4 * 4 + 3];
                    }
                    acc2[u] += s2;
                }
            }
            #pragma unroll
            for (int u = 0; u < 4; ++u) {
                int t = half * 32 + q * 4 + u;
                y[((size_t)br * T_ + t) * OUT_ + o] = acc2[u];
            }
        }
        __syncthreads();
    }
}

extern "C" void kernel_launch(void* const* d_in, const int* in_sizes, int n_in,
                              void* d_out, int out_size, void* d_ws, size_t ws_size,
                              hipStream_t stream) {
    const float* node_feats = (const float*)d_in[0];
    const float* eps_       = (const float*)d_in[1];
    const float* space_w    = (const float*)d_in[2];
    const int*   src        = (const int*)d_in[3];
    const int*   dst        = (const int*)d_in[4];
    const float* W_e1 = (const float*)d_in[5];
    const float* b_e1 = (const float*)d_in[6];
    const float* W_e2 = (const float*)d_in[7];
    const float* b_e2 = (const float*)d_in[8];
    const float* W_mu = (const float*)d_in[9];
    const float* W_sig = (const float*)d_in[10];
    const float* W_msg = (const float*)d_in[11];
    const float* W_self = (const float*)d_in[12];
    const float* W_dyn = (const float*)d_in[13];
    const float* b_ode = (const float*)d_in[14];
    const float* W_d1 = (const float*)d_in[15];
    const float* b_d1 = (const float*)d_in[16];
    const float* W_d2 = (const float*)d_in[17];
    const float* b_d2 = (const float*)d_in[18];
    float* out = (float*)d_out;

    float* f_ws = (float*)d_ws;
    float* Lz    = f_ws;                              // 65536
    float* Dz    = Lz + B_ * R_ * L_;                 // 65536
    float* dynb  = Dz + B_ * R_ * D_;                 // 65536
    float* traj  = dynb + B_ * R_ * L_;               // 4194304
    float* wperm = traj + (size_t)B_ * T_ * R_ * L_;  // 16384
    int* row_start = (int*)(wperm + B_ * ES_);        // 132
    int* esrcp     = row_start + 132;                 // 2048

    prep_kernel<<<1, 128, 0, stream>>>(src, dst, space_w, row_start, esrcp, wperm);
    encoder_kernel<<<B_ * R_, 256, 0, stream>>>(node_feats, eps_, W_e1, b_e1, W_e2, b_e2,
                                                W_mu, W_sig, W_dyn, Lz, Dz, dynb);
    ode_kernel<<<B_, 512, ODE_LDS, stream>>>(Lz, dynb, W_msg, W_self, b_ode,
                                             row_start, esrcp, wperm, traj);
    decoder_kernel<<<B_ * R_, 256, 0, stream>>>(traj, Dz, W_d1, b_d1, W_d2, b_d2, out);
}